// Round 7
// baseline (244.213 us; speedup 1.0000x reference)
//
#include <hip/hip_runtime.h>
#include <math.h>

// ---------------------------------------------------------------------------
// LSGC: B=32, C=128, H=W=64. N_pixels = 32*64*64 = 131072.
// Intermediates are bf16 "k-pair" dwords (d = bf16[2c] | bf16[2c+1]<<16) in a
// TILED layout: tile bx = (b<<6)|hwblk is 4096 contiguous dwords [k2=0..63]
// [col=0..63] (16 KB). GEMM tile fetch/store = dense sequential 16 KB (r6:
// the [b][k2][hw] layout scattered every tile into 64 x 256B chunks at 16KB
// stride -> 2.45 TB/s plateau). The layout transpose cost moves to stencil
// writes (full 128B lines) and epilogue reads (L3-resident).
//   1) stencil: fmax = x - min(...); emits x/fmax pair-tiles (+w prep)
//      LDS XOR bank swizzle (col4 ^= row&7): kills 4.45M conflicts (r6).
//   2) gemm1 dual (persistent, 4 tiles/block) -> y tiles (+BN partials)
//   3) reduce + finalize1 -> w_eff
//   4) gemm2 (persistent, 2 tiles/block, K=256) -> h tiles (+BN partials)
//   5) reduce2 ; 6) epilogue (folds finalize2) -> fp32 out
// GEMM staging: global_load_lds w16 into linear LDS, bank swizzle folded into
// the per-lane GLOBAL source col (^ i<<4) + same XOR on ds_read (0 conflicts,
// r6). One barrier per 16KB stage; stage issued right after the barrier that
// frees its buffer. C-write of tile t deferred into tile t+1's compute.
// Persistent blocks keep L2 lines until fully dirty (r5: no write-amp).
// Stats = non-atomic per-tile partials. A-side hi/lo split for fp32-grade w.
// ---------------------------------------------------------------------------

#define INV_NPIX (1.0f / 131072.0f)
#define EPS 1e-5f
#define T1 4  // tiles per block, gemm1
#define T2 2  // tiles per block, gemm2

typedef __attribute__((ext_vector_type(8))) short s16x8;
typedef __attribute__((ext_vector_type(4))) float f32x4;

__device__ __forceinline__ uint32_t bf16_rne(float v) {
  uint32_t x = __float_as_uint(v);
  return (x + 0x7fffu + ((x >> 16) & 1u)) >> 16;
}
__device__ __forceinline__ uint32_t pack_hl(float v) {
  uint32_t h = bf16_rne(v);
  float lo = v - __uint_as_float(h << 16);
  return h | (bf16_rne(lo) << 16);
}
__device__ __forceinline__ float bf_lo(uint32_t d) {
  return __uint_as_float(d << 16);
}
__device__ __forceinline__ float bf_hi(uint32_t d) {
  return __uint_as_float(d & 0xffff0000u);
}
__device__ __forceinline__ float4 fmin4(float4 a, float4 b) {
  return make_float4(fminf(a.x, b.x), fminf(a.y, b.y), fminf(a.z, b.z),
                     fminf(a.w, b.w));
}

// swizzled LDS accessor: plane position (row hh, float4-col ww) ->
// [((hh&63)<<4) | ((ww&15) ^ (hh&7))]  ((x&63)&7 == x&7 since 64 = 0 mod 8)
#define RD(P, hh, ww) P[(((hh) & 63) << 4) | (((ww) & 15) ^ ((hh) & 7))]

// ------------- stencil (2 planes/block) + pair-pack + prep ------------------
__global__ __launch_bounds__(256) void stencil_prep_kernel(
    const float* __restrict__ x, uint32_t* __restrict__ xp,
    uint32_t* __restrict__ fp, const float* __restrict__ w_in,
    const float* __restrict__ w_diff, unsigned short* __restrict__ wInH,
    unsigned short* __restrict__ wInL, unsigned short* __restrict__ wDfH,
    unsigned short* __restrict__ wDfL) {
  __shared__ float4 pA[1024];
  __shared__ float4 pB[1024];
  if (blockIdx.x >= 2048) {
    const int t = (blockIdx.x - 2048) * 256 + threadIdx.x;  // 0..32767
    const int e = t & 16383;
    const float* w = (t < 16384) ? w_in : w_diff;
    unsigned short* aH = (t < 16384) ? wInH : wDfH;
    unsigned short* aL = (t < 16384) ? wInL : wDfL;
    const int j = e & 7, l = (e >> 3) & 63, mt = (e >> 9) & 7, kc = e >> 12;
    const int m = mt * 16 + (l & 15);
    const int k = kc * 32 + ((l >> 4) << 3) + j;
    const uint32_t p = pack_hl(w[m * 128 + k]);
    aH[e] = (unsigned short)(p & 0xffffu);
    aL[e] = (unsigned short)(p >> 16);
    return;
  }
  const int b = blockIdx.x >> 6;
  const int cp = blockIdx.x & 63;
  const float4* xa = (const float4*)x + (size_t)(b * 128 + 2 * cp) * 1024;
  const float4* xb = xa + 1024;
  float4 sA[4], sB[4];
#pragma unroll
  for (int i = 0; i < 4; ++i) {
    const int u = threadIdx.x + i * 256;
    const int h = u >> 4, wu = u & 15;
    sA[i] = xa[u];
    sB[i] = xb[u];
    RD(pA, h, wu) = sA[i];
    RD(pB, h, wu) = sB[i];
  }
  __syncthreads();
#pragma unroll
  for (int i = 0; i < 4; ++i) {
    const int u = threadIdx.x + i * 256;
    const int h = u >> 4, wu = u & 15;
    float4 mA, mB;
    {
      const float4 A = sA[i];
      const float4 L = RD(pA, h, wu + 15);
      const float4 R = RD(pA, h, wu + 1);
      float4 m = fmin4(A, fmin4(L, R));
      m = fmin4(m, make_float4(A.z, A.w, R.x, R.y));
      m = fmin4(m, make_float4(L.z, L.w, A.x, A.y));
      m = fmin4(m, RD(pA, h, wu + 2));
      m = fmin4(m, RD(pA, h, wu + 14));
      m = fmin4(m, RD(pA, h, wu + 4));
      m = fmin4(m, RD(pA, h, wu + 12));
      m = fmin4(m, RD(pA, h, wu + 8));
      m = fmin4(m, RD(pA, h + 2, wu));
      m = fmin4(m, RD(pA, h + 62, wu));
      m = fmin4(m, RD(pA, h + 4, wu));
      m = fmin4(m, RD(pA, h + 60, wu));
      m = fmin4(m, RD(pA, h + 8, wu));
      m = fmin4(m, RD(pA, h + 56, wu));
      m = fmin4(m, RD(pA, h + 16, wu));
      m = fmin4(m, RD(pA, h + 48, wu));
      m = fmin4(m, RD(pA, h + 32, wu));
      mA = m;
    }
    {
      const float4 A = sB[i];
      const float4 L = RD(pB, h, wu + 15);
      const float4 R = RD(pB, h, wu + 1);
      float4 m = fmin4(A, fmin4(L, R));
      m = fmin4(m, make_float4(A.z, A.w, R.x, R.y));
      m = fmin4(m, make_float4(L.z, L.w, A.x, A.y));
      m = fmin4(m, RD(pB, h, wu + 2));
      m = fmin4(m, RD(pB, h, wu + 14));
      m = fmin4(m, RD(pB, h, wu + 4));
      m = fmin4(m, RD(pB, h, wu + 12));
      m = fmin4(m, RD(pB, h, wu + 8));
      m = fmin4(m, RD(pB, h + 2, wu));
      m = fmin4(m, RD(pB, h + 62, wu));
      m = fmin4(m, RD(pB, h + 4, wu));
      m = fmin4(m, RD(pB, h + 60, wu));
      m = fmin4(m, RD(pB, h + 8, wu));
      m = fmin4(m, RD(pB, h + 56, wu));
      m = fmin4(m, RD(pB, h + 16, wu));
      m = fmin4(m, RD(pB, h + 48, wu));
      m = fmin4(m, RD(pB, h + 32, wu));
      mB = m;
    }
    uint4 px, pf;
    px.x = bf16_rne(sA[i].x) | (bf16_rne(sB[i].x) << 16);
    px.y = bf16_rne(sA[i].y) | (bf16_rne(sB[i].y) << 16);
    px.z = bf16_rne(sA[i].z) | (bf16_rne(sB[i].z) << 16);
    px.w = bf16_rne(sA[i].w) | (bf16_rne(sB[i].w) << 16);
    pf.x = bf16_rne(sA[i].x - mA.x) | (bf16_rne(sB[i].x - mB.x) << 16);
    pf.y = bf16_rne(sA[i].y - mA.y) | (bf16_rne(sB[i].y - mB.y) << 16);
    pf.z = bf16_rne(sA[i].z - mA.z) | (bf16_rne(sB[i].z - mB.z) << 16);
    pf.w = bf16_rne(sA[i].w - mA.w) | (bf16_rne(sB[i].w - mB.w) << 16);
    // tiled write: tile (b, hwblk=u>>4), row cp, float4-col u&15
    const size_t o = (size_t)(b * 64 + (u >> 4)) * 1024 + cp * 16 + (u & 15);
    ((uint4*)xp)[o] = px;
    ((uint4*)fp)[o] = pf;
  }
}

// ------------------ async stage: global -> LDS (swizzled src) ----------------
// Tile bx = 4096 contiguous dwords [row=k2][col]. Wave w stages rows
// 16w..16w+15 with 4 gload_lds (1KB each, dense). Source col xored by i<<4 so
// LDS[row][c] = G[row][c ^ (((row>>2)&3)<<4)]; read applies the same XOR.
__device__ __forceinline__ void stage_tile(const uint32_t* __restrict__ B,
                                           const int bx, uint32_t* lbuf,
                                           const int wave, const int lane) {
  const int qq = lane >> 4, ln = lane & 15;
#pragma unroll
  for (int i = 0; i < 4; ++i) {
    const int row = wave * 16 + i * 4 + qq;
    const uint32_t* src = &B[(size_t)bx * 4096 + row * 64 + ((ln * 4) ^ (i << 4))];
    uint32_t* dst = lbuf + (wave * 16 + i * 4) * 64;  // wave-uniform base
    __builtin_amdgcn_global_load_lds(
        (const __attribute__((address_space(1))) void*)src,
        (__attribute__((address_space(3))) void*)dst, 16, 0, 0);
  }
}

// --------------------------- C-write + stats ---------------------------------
__device__ __forceinline__ void cwrite_stats(
    const f32x4 (&acc)[2][4], uint32_t* __restrict__ outp,
    float* __restrict__ pS, float* __restrict__ pQ, const int bx,
    const int wave, const int q, const int ln) {
#pragma unroll
  for (int mt2 = 0; mt2 < 2; ++mt2) {
    float sa[4] = {0.f, 0.f, 0.f, 0.f};
    float sq[4] = {0.f, 0.f, 0.f, 0.f};
#pragma unroll
    for (int nt = 0; nt < 4; ++nt) {
#pragma unroll
      for (int rp = 0; rp < 2; ++rp) {
        const float v0 = acc[mt2][nt][2 * rp];
        const float v1 = acc[mt2][nt][2 * rp + 1];
        const int m2 = (wave * 2 + mt2) * 8 + q * 2 + rp;
        outp[(size_t)bx * 4096 + m2 * 64 + nt * 16 + ln] =
            bf16_rne(v0) | (bf16_rne(v1) << 16);
        sa[2 * rp] += v0;
        sq[2 * rp] += v0 * v0;
        sa[2 * rp + 1] += v1;
        sq[2 * rp + 1] += v1 * v1;
      }
    }
#pragma unroll
    for (int off = 1; off < 16; off <<= 1) {
#pragma unroll
      for (int r = 0; r < 4; ++r) {
        sa[r] += __shfl_xor(sa[r], off);
        sq[r] += __shfl_xor(sq[r], off);
      }
    }
    if (ln == 0) {
#pragma unroll
      for (int r = 0; r < 4; ++r) {
        const int m = (wave * 2 + mt2) * 16 + q * 4 + r;
        pS[bx * 128 + m] = sa[r];
        pQ[bx * 128 + m] = sq[r];
      }
    }
  }
}

// --------------------------- gemm1 persistent (K=128) ------------------------
template <int T>
__device__ __forceinline__ void gemm1_persist(
    const unsigned short* __restrict__ AH, const unsigned short* __restrict__ AL,
    const uint32_t* __restrict__ B0, uint32_t* __restrict__ outp,
    float* __restrict__ pS, float* __restrict__ pQ, const int p,
    uint32_t* Bs) {
  const int tid = threadIdx.x;
  const int lane = tid & 63;
  const int wave = tid >> 6;
  const int q = lane >> 4;
  const int ln = lane & 15;

  stage_tile(B0, p * T, Bs, wave, lane);

  f32x4 accA[2][4], accB[2][4];

#pragma unroll
  for (int t = 0; t < T; ++t) {
    const int bx = p * T + t;
    uint32_t* buf = Bs + (t & 1) * 4096;
    __syncthreads();  // drains gloads for buf (+ prev tile's stores)
    if (t + 1 < T) stage_tile(B0, bx + 1, Bs + ((t + 1) & 1) * 4096, wave, lane);
    s16x8 ah[2][2], al[2][2];
#pragma unroll
    for (int mt2 = 0; mt2 < 2; ++mt2) {
      const size_t off = ((size_t)((wave * 2 + mt2) * 64 + lane)) << 3;
      ah[0][mt2] = *(const s16x8*)(AH + off);
      al[0][mt2] = *(const s16x8*)(AL + off);
    }
    // deferred C-write of previous tile: stores drain during this compute
    if (t > 0)
      cwrite_stats((t & 1) ? accA : accB, outp, pS, pQ, bx - 1, wave, q, ln);
    f32x4(&acc)[2][4] = (t & 1) ? accB : accA;
#pragma unroll
    for (int i = 0; i < 2; ++i)
#pragma unroll
      for (int jj = 0; jj < 4; ++jj) acc[i][jj] = (f32x4)(0.0f);
#pragma unroll
    for (int kc = 0; kc < 4; ++kc) {
      if (kc < 3) {
#pragma unroll
        for (int mt2 = 0; mt2 < 2; ++mt2) {
          const size_t off =
              ((size_t)(((kc + 1) * 8 + wave * 2 + mt2) * 64 + lane)) << 3;
          ah[(kc + 1) & 1][mt2] = *(const s16x8*)(AH + off);
          al[(kc + 1) & 1][mt2] = *(const s16x8*)(AL + off);
        }
      }
#pragma unroll
      for (int nt = 0; nt < 4; ++nt) {
        union { uint32_t u[4]; s16x8 s; } bb;
#pragma unroll
        for (int j = 0; j < 4; ++j)
          bb.u[j] =
              buf[(kc * 16 + q * 4 + j) * 64 + ((nt * 16 + ln) ^ (q << 4))];
#pragma unroll
        for (int mt2 = 0; mt2 < 2; ++mt2) {
          acc[mt2][nt] = __builtin_amdgcn_mfma_f32_16x16x32_bf16(
              ah[kc & 1][mt2], bb.s, acc[mt2][nt], 0, 0, 0);
          acc[mt2][nt] = __builtin_amdgcn_mfma_f32_16x16x32_bf16(
              al[kc & 1][mt2], bb.s, acc[mt2][nt], 0, 0, 0);
        }
      }
    }
  }
  cwrite_stats(((T - 1) & 1) ? accB : accA, outp, pS, pQ, p * T + T - 1, wave,
               q, ln);
}

__global__ __launch_bounds__(256) void gemm1_dual(
    const unsigned short* __restrict__ AH1, const unsigned short* __restrict__ AL1,
    const uint32_t* __restrict__ XP, uint32_t* __restrict__ out1,
    float* __restrict__ sv1, float* __restrict__ sq1,
    const unsigned short* __restrict__ AH2, const unsigned short* __restrict__ AL2,
    const uint32_t* __restrict__ FP, uint32_t* __restrict__ out2,
    float* __restrict__ sv2, float* __restrict__ sq2) {
  __shared__ uint32_t Bs[2 * 4096];
  const int p = blockIdx.x & 511;
  if (blockIdx.x < 512)
    gemm1_persist<T1>(AH1, AL1, XP, out1, sv1, sq1, p, Bs);
  else
    gemm1_persist<T1>(AH2, AL2, FP, out2, sv2, sq2, p, Bs);
}

// --------------------------- gemm2 persistent (K=256) ------------------------
template <int T>
__device__ __forceinline__ void gemm2_persist(
    const unsigned short* __restrict__ AH, const unsigned short* __restrict__ AL,
    const uint32_t* __restrict__ B0, const uint32_t* __restrict__ B1,
    uint32_t* __restrict__ outp, float* __restrict__ pS,
    float* __restrict__ pQ, const int p, uint32_t* Bs) {
  const int tid = threadIdx.x;
  const int lane = tid & 63;
  const int wave = tid >> 6;
  const int q = lane >> 4;
  const int ln = lane & 15;

  stage_tile(B0, p * T, Bs, wave, lane);

  f32x4 accA[2][4], accB[2][4];

#pragma unroll
  for (int s = 0; s < 2 * T; ++s) {
    const int t = s >> 1, half = s & 1;
    const int bx = p * T + t;
    uint32_t* buf = Bs + (s & 1) * 4096;
    __syncthreads();
    if (s + 1 < 2 * T) {
      const int s2 = s + 1;
      stage_tile((s2 & 1) ? B1 : B0, p * T + (s2 >> 1), Bs + (s2 & 1) * 4096,
                 wave, lane);
    }
    const int kb = half * 4;  // first global k-chunk of this stage
    s16x8 ah[2][2], al[2][2];
#pragma unroll
    for (int mt2 = 0; mt2 < 2; ++mt2) {
      const size_t off = ((size_t)((kb * 8 + wave * 2 + mt2) * 64 + lane)) << 3;
      ah[0][mt2] = *(const s16x8*)(AH + off);
      al[0][mt2] = *(const s16x8*)(AL + off);
    }
    f32x4(&acc)[2][4] = (t & 1) ? accB : accA;
    if (half == 0) {
      if (t > 0)
        cwrite_stats((t & 1) ? accA : accB, outp, pS, pQ, bx - 1, wave, q, ln);
#pragma unroll
      for (int i = 0; i < 2; ++i)
#pragma unroll
        for (int jj = 0; jj < 4; ++jj) acc[i][jj] = (f32x4)(0.0f);
    }
#pragma unroll
    for (int kc = 0; kc < 4; ++kc) {
      if (kc < 3) {
#pragma unroll
        for (int mt2 = 0; mt2 < 2; ++mt2) {
          const size_t off =
              ((size_t)(((kb + kc + 1) * 8 + wave * 2 + mt2) * 64 + lane)) << 3;
          ah[(kc + 1) & 1][mt2] = *(const s16x8*)(AH + off);
          al[(kc + 1) & 1][mt2] = *(const s16x8*)(AL + off);
        }
      }
#pragma unroll
      for (int nt = 0; nt < 4; ++nt) {
        union { uint32_t u[4]; s16x8 s; } bb;
#pragma unroll
        for (int j = 0; j < 4; ++j)
          bb.u[j] =
              buf[(kc * 16 + q * 4 + j) * 64 + ((nt * 16 + ln) ^ (q << 4))];
#pragma unroll
        for (int mt2 = 0; mt2 < 2; ++mt2) {
          acc[mt2][nt] = __builtin_amdgcn_mfma_f32_16x16x32_bf16(
              ah[kc & 1][mt2], bb.s, acc[mt2][nt], 0, 0, 0);
          acc[mt2][nt] = __builtin_amdgcn_mfma_f32_16x16x32_bf16(
              al[kc & 1][mt2], bb.s, acc[mt2][nt], 0, 0, 0);
        }
      }
    }
  }
  cwrite_stats(((T - 1) & 1) ? accB : accA, outp, pS, pQ, p * T + T - 1, wave,
               q, ln);
}

__global__ __launch_bounds__(256) void gemm2_kernel(
    const unsigned short* __restrict__ AH, const unsigned short* __restrict__ AL,
    const uint32_t* __restrict__ B0, const uint32_t* __restrict__ B1,
    uint32_t* __restrict__ outp, float* __restrict__ sv,
    float* __restrict__ sq) {
  __shared__ uint32_t Bs[2 * 4096];
  gemm2_persist<T2>(AH, AL, B0, B1, outp, sv, sq, blockIdx.x, Bs);
}

// --------------------------- stats reduce -----------------------------------
__global__ __launch_bounds__(256) void reduce_kernel(
    const float* __restrict__ P, float* __restrict__ p2) {
  const int a = blockIdx.x >> 4, g = blockIdx.x & 15;
  const int c = threadIdx.x & 127, h = threadIdx.x >> 7;
  const float* src = P + ((size_t)(a * 2048 + g * 128 + h * 64)) * 128 + c;
  float s0 = 0.f, s1 = 0.f, s2 = 0.f, s3 = 0.f;
#pragma unroll
  for (int j = 0; j < 64; j += 4) {
    s0 += src[(j + 0) * 128];
    s1 += src[(j + 1) * 128];
    s2 += src[(j + 2) * 128];
    s3 += src[(j + 3) * 128];
  }
  __shared__ float sm[256];
  sm[threadIdx.x] = (s0 + s1) + (s2 + s3);
  __syncthreads();
  if (h == 0) p2[(a * 16 + g) * 128 + c] = sm[c] + sm[128 + c];
}

// --------------------------- finalize1 ---------------------------------------
__global__ __launch_bounds__(256) void finalize1_kernel(
    const float* __restrict__ p2, const float* __restrict__ g_ibn,
    const float* __restrict__ be_ibn, const float* __restrict__ g_bn,
    const float* __restrict__ w_mr, float* __restrict__ a_in,
    float* __restrict__ d_in, unsigned short* __restrict__ wEffH,
    unsigned short* __restrict__ wEffL) {
  __shared__ float sa[256];
  const int t = threadIdx.x;
  if (t < 128) {
    float s = 0.f, qq = 0.f;
#pragma unroll
    for (int g = 0; g < 16; ++g) {
      s += p2[g * 128 + t];
      qq += p2[(16 + g) * 128 + t];
    }
    const float mu = s * INV_NPIX;
    const float var = fmaxf(qq * INV_NPIX - mu * mu, 0.f);
    const float a = g_ibn[t] * rsqrtf(var + EPS);
    if (blockIdx.x == 0) {
      a_in[t] = a;
      d_in[t] = be_ibn[t] - mu * a;
    }
    sa[t] = a;
  } else {
    const int c = t - 128;
    float s = 0.f, qq = 0.f;
#pragma unroll
    for (int g = 0; g < 16; ++g) {
      s += p2[(32 + g) * 128 + c];
      qq += p2[(48 + g) * 128 + c];
    }
    const float mu = s * INV_NPIX;
    const float var = fmaxf(qq * INV_NPIX - mu * mu, 0.f);
    sa[t] = g_bn[c] * rsqrtf(var + EPS);
  }
  __syncthreads();
  const int e = blockIdx.x * 256 + t;
  const int j = e & 7, l = (e >> 3) & 63, mt = (e >> 9) & 7, kc = e >> 12;
  const int m = mt * 16 + (l & 15);
  const int k = kc * 32 + ((l >> 4) << 3) + j;
  const uint32_t p = pack_hl(w_mr[m * 256 + k] * sa[k]);
  wEffH[e] = (unsigned short)(p & 0xffffu);
  wEffL[e] = (unsigned short)(p >> 16);
}

// --------------------------- epilogue (folds finalize2) ----------------------
__device__ __forceinline__ float gelu_exact(float z) {
  return 0.5f * z * (1.0f + erff(z * 0.70710678118654752f));
}

__global__ __launch_bounds__(256) void epilogue_kernel(
    const uint32_t* __restrict__ yp, const uint32_t* __restrict__ hp,
    const float* __restrict__ a_in, const float* __restrict__ d_in,
    const float* __restrict__ p2h, const float* __restrict__ g_mbn,
    const float* __restrict__ be_mbn, float* __restrict__ out) {
  __shared__ float sAi[128], sDi[128], sAm[128], sDm[128];
  const int tid = threadIdx.x;
  if (tid < 128) {
    float s = 0.f, qq = 0.f;
#pragma unroll
    for (int g = 0; g < 16; ++g) {
      s += p2h[g * 128 + tid];
      qq += p2h[(16 + g) * 128 + tid];
    }
    const float mu = s * INV_NPIX;
    const float var = fmaxf(qq * INV_NPIX - mu * mu, 0.f);
    const float a = g_mbn[tid] * rsqrtf(var + EPS);
    sAm[tid] = a;
    sDm[tid] = be_mbn[tid] - mu * a;
    sAi[tid] = a_in[tid];
    sDi[tid] = d_in[tid];
  }
  __syncthreads();
#pragma unroll
  for (int it = 0; it < 4; ++it) {
    const size_t i = (size_t)(blockIdx.x * 4 + it) * 256 + tid;  // logical idx
    const int cp = (int)((i >> 10) & 63);
    const int b = (int)(i >> 16);
    const int u = (int)(i & 1023);  // float4-col over hw
    const int c0 = 2 * cp, c1 = 2 * cp + 1;
    // tiled read: tile (b, u>>4), row cp, float4-col u&15 (L3-resident)
    const size_t rp4 = (size_t)(b * 64 + (u >> 4)) * 1024 + cp * 16 + (u & 15);
    const uint4 yv = ((const uint4*)yp)[rp4];
    const uint4 hv = ((const uint4*)hp)[rp4];
    const float a0 = sAi[c0], d0 = sDi[c0], m0 = sAm[c0], e0 = sDm[c0];
    const float a1 = sAi[c1], d1 = sDi[c1], m1 = sAm[c1], e1 = sDm[c1];
    float4 o0, o1;
    o0.x = fmaf(a0, bf_lo(yv.x), d0) + gelu_exact(fmaf(m0, bf_lo(hv.x), e0));
    o0.y = fmaf(a0, bf_lo(yv.y), d0) + gelu_exact(fmaf(m0, bf_lo(hv.y), e0));
    o0.z = fmaf(a0, bf_lo(yv.z), d0) + gelu_exact(fmaf(m0, bf_lo(hv.z), e0));
    o0.w = fmaf(a0, bf_lo(yv.w), d0) + gelu_exact(fmaf(m0, bf_lo(hv.w), e0));
    o1.x = fmaf(a1, bf_hi(yv.x), d1) + gelu_exact(fmaf(m1, bf_hi(hv.x), e1));
    o1.y = fmaf(a1, bf_hi(yv.y), d1) + gelu_exact(fmaf(m1, bf_hi(hv.y), e1));
    o1.z = fmaf(a1, bf_hi(yv.z), d1) + gelu_exact(fmaf(m1, bf_hi(hv.z), e1));
    o1.w = fmaf(a1, bf_hi(yv.w), d1) + gelu_exact(fmaf(m1, bf_hi(hv.w), e1));
    ((float4*)out)[(size_t)(b * 128 + c0) * 1024 + u] = o0;
    ((float4*)out)[(size_t)(b * 128 + c1) * 1024 + u] = o1;
  }
}

// --------------------------- launch -----------------------------------------
extern "C" void kernel_launch(void* const* d_in, const int* in_sizes, int n_in,
                              void* d_out, int out_size, void* d_ws,
                              size_t ws_size, hipStream_t stream) {
  const float* x = (const float*)d_in[0];
  const float* w_diff = (const float*)d_in[1];
  const float* g_bn = (const float*)d_in[3];
  const float* w_in = (const float*)d_in[5];
  const float* g_ibn = (const float*)d_in[7];
  const float* be_ibn = (const float*)d_in[8];
  const float* w_mr = (const float*)d_in[9];
  const float* g_mbn = (const float*)d_in[11];
  const float* be_mbn = (const float*)d_in[12];
  float* out = (float*)d_out;

  const size_t PD = (size_t)8388608;  // 32*64*4096 pair-dwords per tensor
  uint32_t* ws = (uint32_t*)d_ws;
  uint32_t* xp = ws;             // x pair-tiles
  uint32_t* fpx = ws + PD;       // fmax pair-tiles
  uint32_t* ypIn = ws + 2 * PD;  // y_in pair-tiles
  uint32_t* ypDf = ws + 3 * PD;  // y_df pair-tiles
  uint32_t* hp = ws + 4 * PD;    // h pair-tiles
  float* st = (float*)(ws + 5 * PD);
  float* p2 = st;          // [4][16][128]
  float* p2h = st + 8192;  // [2][16][128]
  float* a_in = st + 12288, *dinc = st + 12416;
  unsigned short* fr = (unsigned short*)(st + 12800);
  unsigned short* wInH = fr;  // 16384 each
  unsigned short* wInL = fr + 16384;
  unsigned short* wDfH = fr + 32768;
  unsigned short* wDfL = fr + 49152;
  unsigned short* wEffH = fr + 65536;  // 32768 each
  unsigned short* wEffL = fr + 98304;
  // gemm1 partials in the (not-yet-written) hp region (consumed by reduce1
  // before gemm2 overwrites hp); gemm2 partials in the dead xp region.
  float* g1p = (float*)(ws + 4 * PD);
  float* g2p = (float*)ws;

  stencil_prep_kernel<<<2176, 256, 0, stream>>>(x, xp, fpx, w_in, w_diff,
                                                wInH, wInL, wDfH, wDfL);
  gemm1_dual<<<1024, 256, 0, stream>>>(wInH, wInL, xp, ypIn, g1p,
                                       g1p + 262144, wDfH, wDfL, fpx, ypDf,
                                       g1p + 524288, g1p + 786432);
  reduce_kernel<<<64, 256, 0, stream>>>(g1p, p2);
  finalize1_kernel<<<128, 256, 0, stream>>>(p2, g_ibn, be_ibn, g_bn, w_mr,
                                            a_in, dinc, wEffH, wEffL);
  gemm2_kernel<<<1024, 256, 0, stream>>>(wEffH, wEffL, ypIn, ypDf, hp, g2p,
                                         g2p + 262144);
  reduce_kernel<<<32, 256, 0, stream>>>(g2p, p2h);
  epilogue_kernel<<<2048, 256, 0, stream>>>(ypIn, hp, a_in, dinc, p2h, g_mbn,
                                            be_mbn, out);
}